// Round 4
// baseline (408.598 us; speedup 1.0000x reference)
//
#include <hip/hip_runtime.h>
#include <cstdint>

#define EDIM 1024
#define NHEADS 16
#define HDIM 64
#define BATCH 2
#define SEQ 2048
#define MROWS (BATCH * SEQ) // 4096

typedef __attribute__((ext_vector_type(8))) short bf16x8; // 8 bf16 = 4 VGPR
typedef __attribute__((ext_vector_type(4))) float f32x4;

__device__ __forceinline__ unsigned short f2bf(float f) {
  union { float f; unsigned u; } v; v.f = f;
  unsigned r = v.u + 0x7FFFu + ((v.u >> 16) & 1u); // RNE
  return (unsigned short)(r >> 16);
}

// pack two f32 -> two bf16 (RNE) in one u32 via v_cvt_pk_bf16_f32
__device__ __forceinline__ unsigned cvt_pk_bf16(float lo, float hi) {
  unsigned r;
  asm("v_cvt_pk_bf16_f32 %0, %1, %2" : "=v"(r) : "v"(lo), "v"(hi));
  return r;
}

// async global -> LDS, 16 B per lane (dest = wave-uniform base + lane*16)
__device__ __forceinline__ void gload16(const void* g, void* l) {
  __builtin_amdgcn_global_load_lds(
      (const __attribute__((address_space(1))) unsigned int*)g,
      (__attribute__((address_space(3))) unsigned int*)l, 16, 0, 0);
}

// ---------------------------------------------------------------------------
// fp32 -> bf16 bulk convert (n multiple of 8)
// ---------------------------------------------------------------------------
__global__ __launch_bounds__(256) void cvt_kernel(const float* __restrict__ in,
                                                  unsigned short* __restrict__ out,
                                                  int n) {
  const int i = (blockIdx.x * 256 + threadIdx.x) * 8;
  if (i >= n) return;
  const float4 a = *(const float4*)&in[i];
  const float4 b = *(const float4*)&in[i + 4];
  unsigned short u[8];
  u[0] = f2bf(a.x); u[1] = f2bf(a.y); u[2] = f2bf(a.z); u[3] = f2bf(a.w);
  u[4] = f2bf(b.x); u[5] = f2bf(b.y); u[6] = f2bf(b.z); u[7] = f2bf(b.w);
  *(uint4*)&out[i] = *(uint4*)u;
}

// ---------------------------------------------------------------------------
// bf16 MFMA GEMM NT (m97 structure): C = A @ W^T + bias. 128x128 tile, BK=64,
// linear LDS + global_load_lds width-16 staging. 4 waves (2x2), 64x64/wave.
// MODE 0: scatter to Q(*0.125)/K/V bf16 [B,H,S,D].  MODE 1: +resid, fp32 out.
// ---------------------------------------------------------------------------
template <int MODE>
__global__ __launch_bounds__(256) void gemm_bf16(
    const unsigned short* __restrict__ A, const unsigned short* __restrict__ Bw,
    const float* __restrict__ bias, const float* __restrict__ resid,
    unsigned short* __restrict__ q_out, unsigned short* __restrict__ k_out,
    unsigned short* __restrict__ v_out, float* __restrict__ y_out,
    int M, int N, int K) {
  __shared__ unsigned short As[128 * 64]; // linear [row][k] (gload_lds dest)
  __shared__ unsigned short Bs[128 * 64];
  const int tid = threadIdx.x;
  const int lane = tid & 63, w = tid >> 6;
  const int wr = w >> 1, wc = w & 1;
  const int l15 = lane & 15, g = lane >> 4;
  const int row0 = blockIdx.y * 128, col0 = blockIdx.x * 128;

  // staging map: instr t of wave w covers rows w*32+t*8+(lane>>3), col (lane&7)*8
  const int er = w * 32 + (lane >> 3);
  const int ec = (lane & 7) * 8;

  f32x4 acc[4][4];
#pragma unroll
  for (int i = 0; i < 4; ++i)
#pragma unroll
    for (int j = 0; j < 4; ++j) acc[i][j] = (f32x4){0.f, 0.f, 0.f, 0.f};

  for (int k0 = 0; k0 < K; k0 += 64) {
    __syncthreads(); // prior-iter frag reads complete before overwrite
#pragma unroll
    for (int t = 0; t < 4; ++t) {
      gload16(&A[(size_t)(row0 + er + t * 8) * K + k0 + ec],
              &As[w * 2048 + t * 512]);
      gload16(&Bw[(size_t)(col0 + er + t * 8) * K + k0 + ec],
              &Bs[w * 2048 + t * 512]);
    }
    __syncthreads(); // drains vmcnt: staged tile visible
#pragma unroll
    for (int ks = 0; ks < 2; ++ks) {
      bf16x8 af[4], bfr[4];
#pragma unroll
      for (int i = 0; i < 4; ++i)
        af[i] = *(const bf16x8*)&As[(wr * 64 + i * 16 + l15) * 64 + ks * 32 + g * 8];
#pragma unroll
      for (int j = 0; j < 4; ++j)
        bfr[j] = *(const bf16x8*)&Bs[(wc * 64 + j * 16 + l15) * 64 + ks * 32 + g * 8];
#pragma unroll
      for (int i = 0; i < 4; ++i)
#pragma unroll
        for (int j = 0; j < 4; ++j)
          acc[i][j] = __builtin_amdgcn_mfma_f32_16x16x32_bf16(af[i], bfr[j],
                                                              acc[i][j], 0, 0, 0);
    }
  }

#pragma unroll
  for (int j = 0; j < 4; ++j) {
    const int nbase = col0 + wc * 64 + j * 16 + l15;
    const float bb = bias[nbase];
#pragma unroll
    for (int i = 0; i < 4; ++i) {
#pragma unroll
      for (int r = 0; r < 4; ++r) {
        const int m = row0 + wr * 64 + i * 16 + g * 4 + r;
        float v = acc[i][j][r] + bb;
        if (MODE == 0) {
          const int which = nbase >> 10;
          const int h = (nbase >> 6) & 15, d = nbase & 63;
          const int b = m >> 11, s = m & 2047;
          const size_t idx = ((size_t)(b * NHEADS + h) * SEQ + s) * HDIM + d;
          if (which == 0) q_out[idx] = f2bf(v * 0.125f); // fold 1/sqrt(D)
          else if (which == 1) k_out[idx] = f2bf(v);
          else v_out[idx] = f2bf(v);
        } else {
          v += resid[(size_t)m * N + nbase];
          y_out[(size_t)m * N + nbase] = v;
        }
      }
    }
  }
}

// ---------------------------------------------------------------------------
// V [B,H,S,D] -> Vt [B,H,D,S] tile transpose (64 s-rows per block)
// ---------------------------------------------------------------------------
__global__ __launch_bounds__(256) void vtrans_kernel(
    const unsigned short* __restrict__ V, unsigned short* __restrict__ Vt) {
  __shared__ unsigned short T[64 * 72];
  const int tid = threadIdx.x;
  const int st = blockIdx.x, bh = blockIdx.y;
  const size_t ibase = (size_t)bh * SEQ * HDIM + (size_t)st * 64 * HDIM;
#pragma unroll
  for (int t = 0; t < 2; ++t) {
    const int chunk = t * 256 + tid; // 512 chunks of 16B
    const int r = chunk >> 3, c8 = chunk & 7;
    const uint4 v = *(const uint4*)&V[ibase + r * 64 + c8 * 8];
    *(uint4*)&T[r * 72 + c8 * 8] = v;
  }
  __syncthreads();
  const size_t obase = (size_t)bh * HDIM * SEQ + st * 64;
#pragma unroll
  for (int t = 0; t < 2; ++t) {
    const int chunk = t * 256 + tid;
    const int d = chunk >> 3, s8 = (chunk & 7) * 8;
    unsigned short u[8];
#pragma unroll
    for (int e = 0; e < 8; ++e) u[e] = T[(s8 + e) * 72 + d];
    *(uint4*)&Vt[obase + (size_t)d * SEQ + s8] = *(uint4*)u;
  }
}

// ---------------------------------------------------------------------------
// Flash attention, bf16 MFMA. Block = 4 waves, QBLK=64 (16 q-rows/wave),
// KV tile 64. Grid 32x32 = 1024 blocks -> 4 blocks/CU (2x round-3 occupancy).
// Q in regs; K, V^T frags from global (L2-resident); P via wave-private LDS
// (no barriers in k-loop). P converted with v_cvt_pk_bf16_f32.
// ---------------------------------------------------------------------------
__global__ __launch_bounds__(256) void attn_mfma(
    const unsigned short* __restrict__ Qb, const unsigned short* __restrict__ Kb,
    const unsigned short* __restrict__ Vt, unsigned short* __restrict__ AO) {
  __shared__ unsigned short P_lds[64 * 72]; // [q_local][key] bf16, 9 KB
  const int tid = threadIdx.x;
  const int lane = tid & 63, w = tid >> 6;
  const int l15 = lane & 15, g = lane >> 4;
  const int qt = blockIdx.x; // 32
  const int bh = blockIdx.y; // 32
  const int b = bh >> 4, h = bh & 15;
  const size_t hbase = (size_t)bh * SEQ * HDIM;
  const size_t vbase = (size_t)bh * HDIM * SEQ;
  const int q0 = qt * 64 + w * 16;

  bf16x8 aq[2];
#pragma unroll
  for (int ks = 0; ks < 2; ++ks)
    aq[ks] = *(const bf16x8*)&Qb[hbase + (size_t)(q0 + l15) * HDIM + ks * 32 + g * 8];

  f32x4 o[4]; // [jd] over d, rows r in regs
  float mi[4], li[4];
#pragma unroll
  for (int jd = 0; jd < 4; ++jd) o[jd] = (f32x4){0.f, 0.f, 0.f, 0.f};
#pragma unroll
  for (int r = 0; r < 4; ++r) { mi[r] = -1e30f; li[r] = 0.f; }

  for (int kt = 0; kt < SEQ / 64; ++kt) {
    f32x4 sc[4];
#pragma unroll
    for (int j = 0; j < 4; ++j) sc[j] = (f32x4){0.f, 0.f, 0.f, 0.f};
#pragma unroll
    for (int ks = 0; ks < 2; ++ks) {
      bf16x8 bk[4];
#pragma unroll
      for (int j = 0; j < 4; ++j)
        bk[j] = *(const bf16x8*)&Kb[hbase + (size_t)(kt * 64 + j * 16 + l15) * HDIM +
                                    ks * 32 + g * 8];
#pragma unroll
      for (int j = 0; j < 4; ++j)
        sc[j] = __builtin_amdgcn_mfma_f32_16x16x32_bf16(aq[ks], bk[j], sc[j], 0, 0, 0);
    }
    // online softmax; q-row = g*4+r, k-col = j*16+l15
    float alpha[4];
#pragma unroll
    for (int r = 0; r < 4; ++r) {
      float tm = fmaxf(fmaxf(sc[0][r], sc[1][r]), fmaxf(sc[2][r], sc[3][r]));
      tm = fmaxf(tm, __shfl_xor(tm, 1));
      tm = fmaxf(tm, __shfl_xor(tm, 2));
      tm = fmaxf(tm, __shfl_xor(tm, 4));
      tm = fmaxf(tm, __shfl_xor(tm, 8));
      const float mn = fmaxf(mi[r], tm);
      const float al = __expf(mi[r] - mn);
      mi[r] = mn;
      float p0 = __expf(sc[0][r] - mn);
      float p1 = __expf(sc[1][r] - mn);
      float p2 = __expf(sc[2][r] - mn);
      float p3 = __expf(sc[3][r] - mn);
      float rs = (p0 + p1) + (p2 + p3);
      rs += __shfl_xor(rs, 1);
      rs += __shfl_xor(rs, 2);
      rs += __shfl_xor(rs, 4);
      rs += __shfl_xor(rs, 8);
      li[r] = li[r] * al + rs;
      alpha[r] = al;
      const unsigned u01 = cvt_pk_bf16(p0, p1);
      const unsigned u23 = cvt_pk_bf16(p2, p3);
      const int prow = (w * 16 + g * 4 + r) * 72;
      P_lds[prow + 0 * 16 + l15] = (unsigned short)u01;
      P_lds[prow + 1 * 16 + l15] = (unsigned short)(u01 >> 16);
      P_lds[prow + 2 * 16 + l15] = (unsigned short)u23;
      P_lds[prow + 3 * 16 + l15] = (unsigned short)(u23 >> 16);
    }
#pragma unroll
    for (int jd = 0; jd < 4; ++jd)
#pragma unroll
      for (int r = 0; r < 4; ++r) o[jd][r] *= alpha[r];
    // PV: A = P (wave-private LDS rows), B = V^T frags from global
#pragma unroll
    for (int ks = 0; ks < 2; ++ks) {
      bf16x8 ap, bv[4];
      ap = *(const bf16x8*)&P_lds[(w * 16 + l15) * 72 + ks * 32 + g * 8];
#pragma unroll
      for (int jd = 0; jd < 4; ++jd)
        bv[jd] = *(const bf16x8*)&Vt[vbase + (size_t)(jd * 16 + l15) * SEQ +
                                     kt * 64 + ks * 32 + g * 8];
#pragma unroll
      for (int jd = 0; jd < 4; ++jd)
        o[jd] = __builtin_amdgcn_mfma_f32_16x16x32_bf16(ap, bv[jd], o[jd], 0, 0, 0);
    }
  }

#pragma unroll
  for (int r = 0; r < 4; ++r) {
    const float inv = 1.f / li[r];
    const int s = qt * 64 + w * 16 + g * 4 + r;
#pragma unroll
    for (int jd = 0; jd < 4; ++jd)
      AO[(size_t)(b * SEQ + s) * EDIM + h * HDIM + jd * 16 + l15] =
          f2bf(o[jd][r] * inv);
  }
}

// ---------------------------------------------------------------------------
// In-place LayerNorm over E=1024, eps=1e-5
// ---------------------------------------------------------------------------
__global__ __launch_bounds__(256) void ln_kernel(float* __restrict__ y,
                                                 const float* __restrict__ gamma,
                                                 const float* __restrict__ beta) {
  const int row = blockIdx.x, tid = threadIdx.x;
  const float4 v = *reinterpret_cast<const float4*>(&y[(size_t)row * EDIM + tid * 4]);
  float s = v.x + v.y + v.z + v.w;
  float s2 = v.x * v.x + v.y * v.y + v.z * v.z + v.w * v.w;
#pragma unroll
  for (int off = 1; off < 64; off <<= 1) {
    s += __shfl_xor(s, off);
    s2 += __shfl_xor(s2, off);
  }
  __shared__ float red[8];
  if ((tid & 63) == 0) {
    red[(tid >> 6) * 2 + 0] = s;
    red[(tid >> 6) * 2 + 1] = s2;
  }
  __syncthreads();
  s = red[0] + red[2] + red[4] + red[6];
  s2 = red[1] + red[3] + red[5] + red[7];
  const float mean = s * (1.f / 1024.f);
  const float var = fmaxf(s2 * (1.f / 1024.f) - mean * mean, 0.f);
  const float rstd = rsqrtf(var + 1e-5f);
  const float4 gm = *reinterpret_cast<const float4*>(&gamma[tid * 4]);
  const float4 be = *reinterpret_cast<const float4*>(&beta[tid * 4]);
  float4 outv;
  outv.x = (v.x - mean) * rstd * gm.x + be.x;
  outv.y = (v.y - mean) * rstd * gm.y + be.y;
  outv.z = (v.z - mean) * rstd * gm.z + be.z;
  outv.w = (v.w - mean) * rstd * gm.w + be.w;
  *reinterpret_cast<float4*>(&y[(size_t)row * EDIM + tid * 4]) = outv;
}

extern "C" void kernel_launch(void* const* d_in, const int* in_sizes, int n_in,
                              void* d_out, int out_size, void* d_ws,
                              size_t ws_size, hipStream_t stream) {
  const float* x = (const float*)d_in[0];
  const float* W_qkv = (const float*)d_in[1];
  const float* b_qkv = (const float*)d_in[2];
  const float* W_proj = (const float*)d_in[3];
  const float* b_proj = (const float*)d_in[4];
  const float* gamma = (const float*)d_in[5];
  const float* beta = (const float*)d_in[6];
  float* out = (float*)d_out;

  uint8_t* p = (uint8_t*)d_ws;
  unsigned short* x_bf = (unsigned short*)p;            p += (size_t)MROWS * EDIM * 2;      // 8 MB
  unsigned short* wqkv_bf = (unsigned short*)p;         p += (size_t)3 * EDIM * EDIM * 2;   // 6 MB
  unsigned short* wproj_bf = (unsigned short*)p;        p += (size_t)EDIM * EDIM * 2;       // 2 MB
  unsigned short* Qb = (unsigned short*)p;              p += (size_t)MROWS * EDIM * 2;      // 8 MB
  unsigned short* Kb = (unsigned short*)p;              p += (size_t)MROWS * EDIM * 2;      // 8 MB
  unsigned short* Vb = (unsigned short*)p;              p += (size_t)MROWS * EDIM * 2;      // 8 MB
  unsigned short* Vtb = (unsigned short*)p;             p += (size_t)MROWS * EDIM * 2;      // 8 MB
  unsigned short* AOb = (unsigned short*)p;             p += (size_t)MROWS * EDIM * 2;      // 8 MB

  // fp32 -> bf16 converts
  cvt_kernel<<<(MROWS * EDIM / 8 + 255) / 256, 256, 0, stream>>>(x, x_bf, MROWS * EDIM);
  cvt_kernel<<<(3 * EDIM * EDIM / 8 + 255) / 256, 256, 0, stream>>>(W_qkv, wqkv_bf, 3 * EDIM * EDIM);
  cvt_kernel<<<(EDIM * EDIM / 8 + 255) / 256, 256, 0, stream>>>(W_proj, wproj_bf, EDIM * EDIM);

  // QKV projection -> Q(*scale)/K/V bf16 [B,H,S,D]
  gemm_bf16<0><<<dim3(24, 32), 256, 0, stream>>>(x_bf, wqkv_bf, b_qkv, nullptr,
                                                 Qb, Kb, Vb, nullptr,
                                                 MROWS, 3 * EDIM, EDIM);
  // V -> V^T [B,H,D,S]
  vtrans_kernel<<<dim3(SEQ / 64, BATCH * NHEADS), 256, 0, stream>>>(Vb, Vtb);
  // flash attention -> AO bf16 [B,S,E]
  attn_mfma<<<dim3(SEQ / 64, BATCH * NHEADS), 256, 0, stream>>>(Qb, Kb, Vtb, AOb);
  // out projection + bias + residual -> fp32 y
  gemm_bf16<1><<<dim3(8, 32), 256, 0, stream>>>(AOb, wproj_bf, b_proj, x,
                                                nullptr, nullptr, nullptr, out,
                                                MROWS, EDIM, EDIM);
  // in-place LayerNorm
  ln_kernel<<<MROWS, 256, 0, stream>>>(out, gamma, beta);
}

// Round 5
// 296.193 us; speedup vs baseline: 1.3795x; 1.3795x over previous
//
#include <hip/hip_runtime.h>
#include <cstdint>

#define EDIM 1024
#define NHEADS 16
#define HDIM 64
#define BATCH 2
#define SEQ 2048
#define MROWS (BATCH * SEQ) // 4096

typedef __attribute__((ext_vector_type(8))) short bf16x8; // 8 bf16 = 4 VGPR
typedef __attribute__((ext_vector_type(4))) float f32x4;

__device__ __forceinline__ unsigned short f2bf(float f) {
  union { float f; unsigned u; } v; v.f = f;
  unsigned r = v.u + 0x7FFFu + ((v.u >> 16) & 1u); // RNE
  return (unsigned short)(r >> 16);
}

// pack two f32 -> two bf16 (RNE) in one u32 via v_cvt_pk_bf16_f32
__device__ __forceinline__ unsigned cvt_pk_bf16(float lo, float hi) {
  unsigned r;
  asm("v_cvt_pk_bf16_f32 %0, %1, %2" : "=v"(r) : "v"(lo), "v"(hi));
  return r;
}

// async global -> LDS, 16 B per lane (dest = wave-uniform base + lane*16)
__device__ __forceinline__ void gload16(const void* g, void* l) {
  __builtin_amdgcn_global_load_lds(
      (const __attribute__((address_space(1))) unsigned int*)g,
      (__attribute__((address_space(3))) unsigned int*)l, 16, 0, 0);
}

// ---------------------------------------------------------------------------
// fp32 -> bf16 bulk convert (n multiple of 8)
// ---------------------------------------------------------------------------
__global__ __launch_bounds__(256) void cvt_kernel(const float* __restrict__ in,
                                                  unsigned short* __restrict__ out,
                                                  int n) {
  const int i = (blockIdx.x * 256 + threadIdx.x) * 8;
  if (i >= n) return;
  const float4 a = *(const float4*)&in[i];
  const float4 b = *(const float4*)&in[i + 4];
  unsigned short u[8];
  u[0] = f2bf(a.x); u[1] = f2bf(a.y); u[2] = f2bf(a.z); u[3] = f2bf(a.w);
  u[4] = f2bf(b.x); u[5] = f2bf(b.y); u[6] = f2bf(b.z); u[7] = f2bf(b.w);
  *(uint4*)&out[i] = *(uint4*)u;
}

// ---------------------------------------------------------------------------
// bf16 MFMA GEMM NT (m97 structure): C = A @ W^T + bias. 128x128 tile, BK=64,
// linear LDS + global_load_lds width-16 staging. 4 waves (2x2), 64x64/wave.
// MODE 0: scatter Q(*0.125)/K -> [B,H,S,D], V -> [B,H,D,S] (transposed!).
// MODE 1: +resid, fp32 out.
// ---------------------------------------------------------------------------
template <int MODE>
__global__ __launch_bounds__(256) void gemm_bf16(
    const unsigned short* __restrict__ A, const unsigned short* __restrict__ Bw,
    const float* __restrict__ bias, const float* __restrict__ resid,
    unsigned short* __restrict__ q_out, unsigned short* __restrict__ k_out,
    unsigned short* __restrict__ vt_out, float* __restrict__ y_out,
    int M, int N, int K) {
  __shared__ unsigned short As[128 * 64]; // linear [row][k] (gload_lds dest)
  __shared__ unsigned short Bs[128 * 64];
  const int tid = threadIdx.x;
  const int lane = tid & 63, w = tid >> 6;
  const int wr = w >> 1, wc = w & 1;
  const int l15 = lane & 15, g = lane >> 4;
  const int row0 = blockIdx.y * 128, col0 = blockIdx.x * 128;

  // staging map: instr t of wave w covers rows w*32+t*8+(lane>>3), col (lane&7)*8
  const int er = w * 32 + (lane >> 3);
  const int ec = (lane & 7) * 8;

  f32x4 acc[4][4];
#pragma unroll
  for (int i = 0; i < 4; ++i)
#pragma unroll
    for (int j = 0; j < 4; ++j) acc[i][j] = (f32x4){0.f, 0.f, 0.f, 0.f};

  for (int k0 = 0; k0 < K; k0 += 64) {
    __syncthreads(); // prior-iter frag reads complete before overwrite
#pragma unroll
    for (int t = 0; t < 4; ++t) {
      gload16(&A[(size_t)(row0 + er + t * 8) * K + k0 + ec],
              &As[w * 2048 + t * 512]);
      gload16(&Bw[(size_t)(col0 + er + t * 8) * K + k0 + ec],
              &Bs[w * 2048 + t * 512]);
    }
    __syncthreads(); // drains vmcnt: staged tile visible
#pragma unroll
    for (int ks = 0; ks < 2; ++ks) {
      bf16x8 af[4], bfr[4];
#pragma unroll
      for (int i = 0; i < 4; ++i)
        af[i] = *(const bf16x8*)&As[(wr * 64 + i * 16 + l15) * 64 + ks * 32 + g * 8];
#pragma unroll
      for (int j = 0; j < 4; ++j)
        bfr[j] = *(const bf16x8*)&Bs[(wc * 64 + j * 16 + l15) * 64 + ks * 32 + g * 8];
#pragma unroll
      for (int i = 0; i < 4; ++i)
#pragma unroll
        for (int j = 0; j < 4; ++j)
          acc[i][j] = __builtin_amdgcn_mfma_f32_16x16x32_bf16(af[i], bfr[j],
                                                              acc[i][j], 0, 0, 0);
    }
  }

#pragma unroll
  for (int j = 0; j < 4; ++j) {
    const int nbase = col0 + wc * 64 + j * 16 + l15;
    const float bb = bias[nbase];
#pragma unroll
    for (int i = 0; i < 4; ++i) {
#pragma unroll
      for (int r = 0; r < 4; ++r) {
        const int m = row0 + wr * 64 + i * 16 + g * 4 + r;
        float v = acc[i][j][r] + bb;
        if (MODE == 0) {
          const int which = nbase >> 10;
          const int h = (nbase >> 6) & 15, d = nbase & 63;
          const int b = m >> 11, s = m & 2047;
          if (which == 0)
            q_out[((size_t)(b * NHEADS + h) * SEQ + s) * HDIM + d] =
                f2bf(v * 0.125f); // fold 1/sqrt(D)
          else if (which == 1)
            k_out[((size_t)(b * NHEADS + h) * SEQ + s) * HDIM + d] = f2bf(v);
          else // V stored transposed: [B,H,D,S]
            vt_out[((size_t)(b * NHEADS + h) * HDIM + d) * SEQ + s] = f2bf(v);
        } else {
          v += resid[(size_t)m * N + nbase];
          y_out[(size_t)m * N + nbase] = v;
        }
      }
    }
  }
}

// ---------------------------------------------------------------------------
// Flash attention, bf16 MFMA. Block = 4 waves, QBLK=128 (32 q-rows/wave),
// KV tile 64. K and V^T staged in LDS ONCE per block (was: every wave loaded
// identical frags from global = 4x redundant), double-buffered, 1 barrier per
// tile, prefetch issued right after the barrier (T3-minimum schedule).
// LDS tiles are XOR-swizzled (both-sides: pre-swizzled global source col +
// swizzled ds_read col) to kill the 16-way row-stride-128B bank conflict.
// ---------------------------------------------------------------------------
__global__ __launch_bounds__(256) void attn_mfma(
    const unsigned short* __restrict__ Qb, const unsigned short* __restrict__ Kb,
    const unsigned short* __restrict__ Vt, unsigned short* __restrict__ AO) {
  __shared__ unsigned short K_lds[2][64 * 64]; // [kv_row][d], swizzled cols
  __shared__ unsigned short V_lds[2][64 * 64]; // [d_row][s], swizzled cols
  __shared__ unsigned short P_lds[128 * 72];   // wave-private P rows
  const int tid = threadIdx.x;
  const int lane = tid & 63, w = tid >> 6;
  const int l15 = lane & 15, g = lane >> 4;
  const int qt = blockIdx.x; // 16
  const int bh = blockIdx.y; // 32
  const int b = bh >> 4, h = bh & 15;
  const size_t hbase = (size_t)bh * SEQ * HDIM;
  const size_t vbase = (size_t)bh * HDIM * SEQ;
  const int q0 = qt * 128 + w * 32;

  // staging geometry: lane covers row r0(+8 for t=1), swizzled source col
  const int r0 = w * 16 + (lane >> 3);
  const int scol = (((lane & 7) ^ (lane >> 3)) & 7) * 8;

  bf16x8 aq[2][2];
#pragma unroll
  for (int i = 0; i < 2; ++i)
#pragma unroll
    for (int ks = 0; ks < 2; ++ks)
      aq[i][ks] = *(const bf16x8*)&Qb[hbase + (size_t)(q0 + i * 16 + l15) * HDIM +
                                      ks * 32 + g * 8];

  f32x4 o[2][4];
  float mi[2][4], li[2][4];
#pragma unroll
  for (int i = 0; i < 2; ++i)
#pragma unroll
    for (int jd = 0; jd < 4; ++jd) o[i][jd] = (f32x4){0.f, 0.f, 0.f, 0.f};
#pragma unroll
  for (int i = 0; i < 2; ++i)
#pragma unroll
    for (int r = 0; r < 4; ++r) { mi[i][r] = -1e30f; li[i][r] = 0.f; }

#define STAGE(buf, kt_)                                                        \
  do {                                                                         \
    gload16(&Kb[hbase + (size_t)((kt_) * 64 + r0) * HDIM + scol],              \
            &K_lds[buf][(w * 16) * 64]);                                       \
    gload16(&Kb[hbase + (size_t)((kt_) * 64 + r0 + 8) * HDIM + scol],          \
            &K_lds[buf][(w * 16 + 8) * 64]);                                   \
    gload16(&Vt[vbase + (size_t)r0 * SEQ + (kt_) * 64 + scol],                 \
            &V_lds[buf][(w * 16) * 64]);                                       \
    gload16(&Vt[vbase + (size_t)(r0 + 8) * SEQ + (kt_) * 64 + scol],           \
            &V_lds[buf][(w * 16 + 8) * 64]);                                   \
  } while (0)

  STAGE(0, 0);
  for (int kt = 0; kt < SEQ / 64; ++kt) {
    const int cur = kt & 1;
    __syncthreads(); // drains vmcnt (buf[cur] staged) + prior reads of buf[cur^1]
    if (kt + 1 < SEQ / 64) STAGE(cur ^ 1, kt + 1); // async, overlaps compute

    f32x4 sc[2][4];
#pragma unroll
    for (int i = 0; i < 2; ++i)
#pragma unroll
      for (int j = 0; j < 4; ++j) sc[i][j] = (f32x4){0.f, 0.f, 0.f, 0.f};
#pragma unroll
    for (int ks = 0; ks < 2; ++ks) {
      bf16x8 bk[4];
#pragma unroll
      for (int j = 0; j < 4; ++j)
        bk[j] = *(const bf16x8*)&K_lds[cur][(j * 16 + l15) * 64 +
                                            (((ks * 4 + g) ^ (l15 & 7)) * 8)];
#pragma unroll
      for (int i = 0; i < 2; ++i)
#pragma unroll
        for (int j = 0; j < 4; ++j)
          sc[i][j] = __builtin_amdgcn_mfma_f32_16x16x32_bf16(aq[i][ks], bk[j],
                                                             sc[i][j], 0, 0, 0);
    }
    // online softmax; q-row = i*16+g*4+r, k-col = j*16+l15
    float alpha[2][4];
#pragma unroll
    for (int i = 0; i < 2; ++i) {
#pragma unroll
      for (int r = 0; r < 4; ++r) {
        float tm = fmaxf(fmaxf(sc[i][0][r], sc[i][1][r]),
                         fmaxf(sc[i][2][r], sc[i][3][r]));
        tm = fmaxf(tm, __shfl_xor(tm, 1));
        tm = fmaxf(tm, __shfl_xor(tm, 2));
        tm = fmaxf(tm, __shfl_xor(tm, 4));
        tm = fmaxf(tm, __shfl_xor(tm, 8));
        const float mn = fmaxf(mi[i][r], tm);
        const float al = __expf(mi[i][r] - mn);
        mi[i][r] = mn;
        float p0 = __expf(sc[i][0][r] - mn);
        float p1 = __expf(sc[i][1][r] - mn);
        float p2 = __expf(sc[i][2][r] - mn);
        float p3 = __expf(sc[i][3][r] - mn);
        float rs = (p0 + p1) + (p2 + p3);
        rs += __shfl_xor(rs, 1);
        rs += __shfl_xor(rs, 2);
        rs += __shfl_xor(rs, 4);
        rs += __shfl_xor(rs, 8);
        li[i][r] = li[i][r] * al + rs;
        alpha[i][r] = al;
        const unsigned u01 = cvt_pk_bf16(p0, p1);
        const unsigned u23 = cvt_pk_bf16(p2, p3);
        const int prow = (w * 32 + i * 16 + g * 4 + r) * 72;
        P_lds[prow + 0 * 16 + l15] = (unsigned short)u01;
        P_lds[prow + 1 * 16 + l15] = (unsigned short)(u01 >> 16);
        P_lds[prow + 2 * 16 + l15] = (unsigned short)u23;
        P_lds[prow + 3 * 16 + l15] = (unsigned short)(u23 >> 16);
      }
    }
#pragma unroll
    for (int i = 0; i < 2; ++i)
#pragma unroll
      for (int jd = 0; jd < 4; ++jd)
#pragma unroll
        for (int r = 0; r < 4; ++r) o[i][jd][r] *= alpha[i][r];
    // PV: A = P (wave-private LDS rows), B = V^T frags from swizzled LDS
#pragma unroll
    for (int ks = 0; ks < 2; ++ks) {
      bf16x8 ap[2], bv[4];
#pragma unroll
      for (int i = 0; i < 2; ++i)
        ap[i] = *(const bf16x8*)&P_lds[(w * 32 + i * 16 + l15) * 72 + ks * 32 + g * 8];
#pragma unroll
      for (int jd = 0; jd < 4; ++jd)
        bv[jd] = *(const bf16x8*)&V_lds[cur][(jd * 16 + l15) * 64 +
                                             (((ks * 4 + g) ^ (l15 & 7)) * 8)];
#pragma unroll
      for (int i = 0; i < 2; ++i)
#pragma unroll
        for (int jd = 0; jd < 4; ++jd)
          o[i][jd] = __builtin_amdgcn_mfma_f32_16x16x32_bf16(ap[i], bv[jd],
                                                             o[i][jd], 0, 0, 0);
    }
  }
#undef STAGE

#pragma unroll
  for (int i = 0; i < 2; ++i) {
#pragma unroll
    for (int r = 0; r < 4; ++r) {
      const float inv = 1.f / li[i][r];
      const int s = qt * 128 + w * 32 + i * 16 + g * 4 + r;
#pragma unroll
      for (int jd = 0; jd < 4; ++jd)
        AO[(size_t)(b * SEQ + s) * EDIM + h * HDIM + jd * 16 + l15] =
            f2bf(o[i][jd][r] * inv);
    }
  }
}

// ---------------------------------------------------------------------------
// In-place LayerNorm over E=1024, eps=1e-5
// ---------------------------------------------------------------------------
__global__ __launch_bounds__(256) void ln_kernel(float* __restrict__ y,
                                                 const float* __restrict__ gamma,
                                                 const float* __restrict__ beta) {
  const int row = blockIdx.x, tid = threadIdx.x;
  const float4 v = *reinterpret_cast<const float4*>(&y[(size_t)row * EDIM + tid * 4]);
  float s = v.x + v.y + v.z + v.w;
  float s2 = v.x * v.x + v.y * v.y + v.z * v.z + v.w * v.w;
#pragma unroll
  for (int off = 1; off < 64; off <<= 1) {
    s += __shfl_xor(s, off);
    s2 += __shfl_xor(s2, off);
  }
  __shared__ float red[8];
  if ((tid & 63) == 0) {
    red[(tid >> 6) * 2 + 0] = s;
    red[(tid >> 6) * 2 + 1] = s2;
  }
  __syncthreads();
  s = red[0] + red[2] + red[4] + red[6];
  s2 = red[1] + red[3] + red[5] + red[7];
  const float mean = s * (1.f / 1024.f);
  const float var = fmaxf(s2 * (1.f / 1024.f) - mean * mean, 0.f);
  const float rstd = rsqrtf(var + 1e-5f);
  const float4 gm = *reinterpret_cast<const float4*>(&gamma[tid * 4]);
  const float4 be = *reinterpret_cast<const float4*>(&beta[tid * 4]);
  float4 outv;
  outv.x = (v.x - mean) * rstd * gm.x + be.x;
  outv.y = (v.y - mean) * rstd * gm.y + be.y;
  outv.z = (v.z - mean) * rstd * gm.z + be.z;
  outv.w = (v.w - mean) * rstd * gm.w + be.w;
  *reinterpret_cast<float4*>(&y[(size_t)row * EDIM + tid * 4]) = outv;
}

extern "C" void kernel_launch(void* const* d_in, const int* in_sizes, int n_in,
                              void* d_out, int out_size, void* d_ws,
                              size_t ws_size, hipStream_t stream) {
  const float* x = (const float*)d_in[0];
  const float* W_qkv = (const float*)d_in[1];
  const float* b_qkv = (const float*)d_in[2];
  const float* W_proj = (const float*)d_in[3];
  const float* b_proj = (const float*)d_in[4];
  const float* gamma = (const float*)d_in[5];
  const float* beta = (const float*)d_in[6];
  float* out = (float*)d_out;

  uint8_t* p = (uint8_t*)d_ws;
  unsigned short* x_bf = (unsigned short*)p;            p += (size_t)MROWS * EDIM * 2;      // 8 MB
  unsigned short* wqkv_bf = (unsigned short*)p;         p += (size_t)3 * EDIM * EDIM * 2;   // 6 MB
  unsigned short* wproj_bf = (unsigned short*)p;        p += (size_t)EDIM * EDIM * 2;       // 2 MB
  unsigned short* Qb = (unsigned short*)p;              p += (size_t)MROWS * EDIM * 2;      // 8 MB
  unsigned short* Kb = (unsigned short*)p;              p += (size_t)MROWS * EDIM * 2;      // 8 MB
  unsigned short* Vtb = (unsigned short*)p;             p += (size_t)MROWS * EDIM * 2;      // 8 MB
  unsigned short* AOb = (unsigned short*)p;             p += (size_t)MROWS * EDIM * 2;      // 8 MB

  // fp32 -> bf16 converts
  cvt_kernel<<<(MROWS * EDIM / 8 + 255) / 256, 256, 0, stream>>>(x, x_bf, MROWS * EDIM);
  cvt_kernel<<<(3 * EDIM * EDIM / 8 + 255) / 256, 256, 0, stream>>>(W_qkv, wqkv_bf, 3 * EDIM * EDIM);
  cvt_kernel<<<(EDIM * EDIM / 8 + 255) / 256, 256, 0, stream>>>(W_proj, wproj_bf, EDIM * EDIM);

  // QKV projection -> Q(*scale)/K [B,H,S,D], V [B,H,D,S]
  gemm_bf16<0><<<dim3(24, 32), 256, 0, stream>>>(x_bf, wqkv_bf, b_qkv, nullptr,
                                                 Qb, Kb, Vtb, nullptr,
                                                 MROWS, 3 * EDIM, EDIM);
  // flash attention -> AO bf16 [B,S,E]
  attn_mfma<<<dim3(SEQ / 128, BATCH * NHEADS), 256, 0, stream>>>(Qb, Kb, Vtb, AOb);
  // out projection + bias + residual -> fp32 y
  gemm_bf16<1><<<dim3(8, 32), 256, 0, stream>>>(AOb, wproj_bf, b_proj, x,
                                                nullptr, nullptr, nullptr, out,
                                                MROWS, EDIM, EDIM);
  // in-place LayerNorm
  ln_kernel<<<MROWS, 256, 0, stream>>>(out, gamma, beta);
}

// Round 10
// 246.008 us; speedup vs baseline: 1.6609x; 1.2040x over previous
//
#include <hip/hip_runtime.h>
#include <cstdint>

#define EDIM 1024
#define NHEADS 16
#define HDIM 64
#define BATCH 2
#define SEQ 2048
#define MROWS (BATCH * SEQ) // 4096

typedef __attribute__((ext_vector_type(8))) short bf16x8; // 8 bf16 = 4 VGPR
typedef __attribute__((ext_vector_type(4))) float f32x4;

__device__ __forceinline__ unsigned short f2bf(float f) {
  union { float f; unsigned u; } v; v.f = f;
  unsigned r = v.u + 0x7FFFu + ((v.u >> 16) & 1u); // RNE
  return (unsigned short)(r >> 16);
}

// pack two f32 -> two bf16 (RNE): D[15:0]=lo, D[31:16]=hi
__device__ __forceinline__ unsigned cvt_pk_bf16(float lo, float hi) {
  unsigned r;
  asm("v_cvt_pk_bf16_f32 %0, %1, %2" : "=v"(r) : "v"(lo), "v"(hi));
  return r;
}

// async global -> LDS, 16 B per lane (dest = wave-uniform base + lane*16)
__device__ __forceinline__ void gload16(const void* g, void* l) {
  __builtin_amdgcn_global_load_lds(
      (const __attribute__((address_space(1))) unsigned int*)g,
      (__attribute__((address_space(3))) unsigned int*)l, 16, 0, 0);
}

// ---------------------------------------------------------------------------
// fp32 -> bf16 bulk convert (n multiple of 8)
// ---------------------------------------------------------------------------
__global__ __launch_bounds__(256) void cvt_kernel(const float* __restrict__ in,
                                                  unsigned short* __restrict__ out,
                                                  int n) {
  const int i = (blockIdx.x * 256 + threadIdx.x) * 8;
  if (i >= n) return;
  const float4 a = *(const float4*)&in[i];
  const float4 b = *(const float4*)&in[i + 4];
  unsigned short u[8];
  u[0] = f2bf(a.x); u[1] = f2bf(a.y); u[2] = f2bf(a.z); u[3] = f2bf(a.w);
  u[4] = f2bf(b.x); u[5] = f2bf(b.y); u[6] = f2bf(b.z); u[7] = f2bf(b.w);
  *(uint4*)&out[i] = *(uint4*)u;
}

// ---------------------------------------------------------------------------
// bf16 MFMA GEMM NT (m97 structure): C = A @ W^T + bias. 128x128 tile, BK=64,
// linear LDS + global_load_lds width-16 staging. 4 waves (2x2), 64x64/wave.
// MODE 0: scatter Q(*0.125)/K/V -> [B,H,S,D].  MODE 1: +resid, fp32 out.
// ---------------------------------------------------------------------------
template <int MODE>
__global__ __launch_bounds__(256) void gemm_bf16(
    const unsigned short* __restrict__ A, const unsigned short* __restrict__ Bw,
    const float* __restrict__ bias, const float* __restrict__ resid,
    unsigned short* __restrict__ q_out, unsigned short* __restrict__ k_out,
    unsigned short* __restrict__ v_out, float* __restrict__ y_out,
    int M, int N, int K) {
  __shared__ unsigned short As[128 * 64]; // linear [row][k] (gload_lds dest)
  __shared__ unsigned short Bs[128 * 64];
  const int tid = threadIdx.x;
  const int lane = tid & 63, w = tid >> 6;
  const int wr = w >> 1, wc = w & 1;
  const int l15 = lane & 15, g = lane >> 4;
  const int row0 = blockIdx.y * 128, col0 = blockIdx.x * 128;

  // staging map: instr t of wave w covers rows w*32+t*8+(lane>>3), col (lane&7)*8
  const int er = w * 32 + (lane >> 3);
  const int ec = (lane & 7) * 8;

  f32x4 acc[4][4];
#pragma unroll
  for (int i = 0; i < 4; ++i)
#pragma unroll
    for (int j = 0; j < 4; ++j) acc[i][j] = (f32x4){0.f, 0.f, 0.f, 0.f};

  for (int k0 = 0; k0 < K; k0 += 64) {
    __syncthreads(); // prior-iter frag reads complete before overwrite
#pragma unroll
    for (int t = 0; t < 4; ++t) {
      gload16(&A[(size_t)(row0 + er + t * 8) * K + k0 + ec],
              &As[w * 2048 + t * 512]);
      gload16(&Bw[(size_t)(col0 + er + t * 8) * K + k0 + ec],
              &Bs[w * 2048 + t * 512]);
    }
    __syncthreads(); // drains vmcnt: staged tile visible
#pragma unroll
    for (int ks = 0; ks < 2; ++ks) {
      bf16x8 af[4], bfr[4];
#pragma unroll
      for (int i = 0; i < 4; ++i)
        af[i] = *(const bf16x8*)&As[(wr * 64 + i * 16 + l15) * 64 + ks * 32 + g * 8];
#pragma unroll
      for (int j = 0; j < 4; ++j)
        bfr[j] = *(const bf16x8*)&Bs[(wc * 64 + j * 16 + l15) * 64 + ks * 32 + g * 8];
#pragma unroll
      for (int i = 0; i < 4; ++i)
#pragma unroll
        for (int j = 0; j < 4; ++j)
          acc[i][j] = __builtin_amdgcn_mfma_f32_16x16x32_bf16(af[i], bfr[j],
                                                              acc[i][j], 0, 0, 0);
    }
  }

#pragma unroll
  for (int j = 0; j < 4; ++j) {
    const int nbase = col0 + wc * 64 + j * 16 + l15;
    const float bb = bias[nbase];
#pragma unroll
    for (int i = 0; i < 4; ++i) {
#pragma unroll
      for (int r = 0; r < 4; ++r) {
        const int m = row0 + wr * 64 + i * 16 + g * 4 + r;
        float v = acc[i][j][r] + bb;
        if (MODE == 0) {
          const int which = nbase >> 10;
          const int h = (nbase >> 6) & 15, d = nbase & 63;
          const int b = m >> 11, s = m & 2047;
          const size_t idx = ((size_t)(b * NHEADS + h) * SEQ + s) * HDIM + d;
          if (which == 0) q_out[idx] = f2bf(v * 0.125f); // fold 1/sqrt(D)
          else if (which == 1) k_out[idx] = f2bf(v);
          else v_out[idx] = f2bf(v);
        } else {
          v += resid[(size_t)m * N + nbase];
          y_out[(size_t)m * N + nbase] = v;
        }
      }
    }
  }
}

// ---------------------------------------------------------------------------
// V [B,H,S,D] -> Vt [B,H,D,S] tile transpose (64 s-rows per block)
// ---------------------------------------------------------------------------
__global__ __launch_bounds__(256) void vtrans_kernel(
    const unsigned short* __restrict__ V, unsigned short* __restrict__ Vt) {
  __shared__ unsigned short T[64 * 72];
  const int tid = threadIdx.x;
  const int st = blockIdx.x, bh = blockIdx.y;
  const size_t ibase = (size_t)bh * SEQ * HDIM + (size_t)st * 64 * HDIM;
#pragma unroll
  for (int t = 0; t < 2; ++t) {
    const int chunk = t * 256 + tid; // 512 chunks of 16B
    const int r = chunk >> 3, c8 = chunk & 7;
    const uint4 v = *(const uint4*)&V[ibase + r * 64 + c8 * 8];
    *(uint4*)&T[r * 72 + c8 * 8] = v;
  }
  __syncthreads();
  const size_t obase = (size_t)bh * HDIM * SEQ + st * 64;
#pragma unroll
  for (int t = 0; t < 2; ++t) {
    const int chunk = t * 256 + tid;
    const int d = chunk >> 3, s8 = (chunk & 7) * 8;
    unsigned short u[8];
#pragma unroll
    for (int e = 0; e < 8; ++e) u[e] = T[(s8 + e) * 72 + d];
    *(uint4*)&Vt[obase + (size_t)d * SEQ + s8] = *(uint4*)u;
  }
}

// ---------------------------------------------------------------------------
// Flash attention, bf16 MFMA, swapped operands (q lives on lane&15 all the
// way through). 8 waves x 16 q-rows = QBLK 128, KV tile 64, K/V^T in LDS
// (double-buffered, XOR-swizzled, global_load_lds), 1 barrier per tile.
//   QK^T: sc_T[j] = mfma(K_frag, Q_frag)  -> lane holds S[q=l15][16 kv vals]
//   softmax: in-lane 16-reduce + 2 shfl(16,32); m/l/alpha are lane scalars
//   PV:    o[jd]  = mfma(V_frag, P_frag)  -> lane holds O[d=g*4+r][q=l15]
// ---------------------------------------------------------------------------
__global__ __launch_bounds__(512, 4) void attn_mfma(
    const unsigned short* __restrict__ Qb, const unsigned short* __restrict__ Kb,
    const unsigned short* __restrict__ Vt, unsigned short* __restrict__ AO) {
  __shared__ unsigned short K_lds[2][64 * 64]; // [kv][d], swizzled cols, 16KB
  __shared__ unsigned short V_lds[2][64 * 64]; // [d][s],  swizzled cols, 16KB
  __shared__ unsigned short P_lds[128 * 80];   // [q][kv] bf16, pad 80, 20KB
  const int tid = threadIdx.x;
  const int lane = tid & 63, w = tid >> 6; // 8 waves
  const int l15 = lane & 15, g = lane >> 4;
  const int qt = blockIdx.x; // 16
  const int bh = blockIdx.y; // 32
  const int b = bh >> 4, h = bh & 15;
  const size_t hbase = (size_t)bh * SEQ * HDIM;
  const size_t vbase = (size_t)bh * HDIM * SEQ;
  const int q = qt * 128 + w * 16 + l15; // this lane's q row
  const int prow = (w * 16 + l15) * 80;  // P_lds row (wave-private span)

  // staging geometry: waves 0-3 stage K rows, waves 4-7 stage V(d) rows
  const int sr = (w & 3) * 16 + (lane >> 3);
  const int scol = ((lane & 7) ^ (lane >> 3)) * 8; // pre-swizzled source col

  bf16x8 aq[2];
#pragma unroll
  for (int ks = 0; ks < 2; ++ks)
    aq[ks] = *(const bf16x8*)&Qb[hbase + (size_t)q * HDIM + ks * 32 + g * 8];

  f32x4 o[4];
#pragma unroll
  for (int jd = 0; jd < 4; ++jd) o[jd] = (f32x4){0.f, 0.f, 0.f, 0.f};
  float mi = -1e30f, li = 0.f;

#define STAGE(buf, kt_)                                                        \
  do {                                                                         \
    if (w < 4) {                                                               \
      gload16(&Kb[hbase + (size_t)((kt_) * 64 + sr) * HDIM + scol],            \
              &K_lds[buf][(w * 16) * 64]);                                     \
      gload16(&Kb[hbase + (size_t)((kt_) * 64 + sr + 8) * HDIM + scol],        \
              &K_lds[buf][(w * 16 + 8) * 64]);                                 \
    } else {                                                                   \
      gload16(&Vt[vbase + (size_t)sr * SEQ + (kt_) * 64 + scol],               \
              &V_lds[buf][((w - 4) * 16) * 64]);                               \
      gload16(&Vt[vbase + (size_t)(sr + 8) * SEQ + (kt_) * 64 + scol],         \
              &V_lds[buf][((w - 4) * 16 + 8) * 64]);                           \
    }                                                                          \
  } while (0)

  STAGE(0, 0);
  for (int kt = 0; kt < SEQ / 64; ++kt) {
    const int cur = kt & 1;
    __syncthreads(); // drains vmcnt (buf[cur] ready) + prior reads of buf[cur^1]
    if (kt + 1 < SEQ / 64) STAGE(cur ^ 1, kt + 1); // async, overlaps compute

    // ---- QK^T (swapped): sc_T[j] row=kv, col=q ----
    f32x4 scT[4];
#pragma unroll
    for (int j = 0; j < 4; ++j) scT[j] = (f32x4){0.f, 0.f, 0.f, 0.f};
    __builtin_amdgcn_s_setprio(1);
#pragma unroll
    for (int ks = 0; ks < 2; ++ks) {
      bf16x8 bk[4];
#pragma unroll
      for (int j = 0; j < 4; ++j)
        bk[j] = *(const bf16x8*)&K_lds[cur][(j * 16 + l15) * 64 +
                                            (((ks * 4 + g) ^ (l15 & 7)) * 8)];
#pragma unroll
      for (int j = 0; j < 4; ++j)
        scT[j] = __builtin_amdgcn_mfma_f32_16x16x32_bf16(bk[j], aq[ks],
                                                         scT[j], 0, 0, 0);
    }
    __builtin_amdgcn_s_setprio(0);

    // ---- online softmax: lane owns q=l15, 16 kv values (j*16+g*4+r) ----
    float tm = scT[0][0];
#pragma unroll
    for (int j = 0; j < 4; ++j)
#pragma unroll
      for (int r = 0; r < 4; ++r) tm = fmaxf(tm, scT[j][r]);
    tm = fmaxf(tm, __shfl_xor(tm, 16));
    tm = fmaxf(tm, __shfl_xor(tm, 32));
    const float mn = fmaxf(mi, tm);
    const float al = __expf(mi - mn);
    mi = mn;
    float p[4][4];
    float rs = 0.f;
#pragma unroll
    for (int j = 0; j < 4; ++j)
#pragma unroll
      for (int r = 0; r < 4; ++r) {
        p[j][r] = __expf(scT[j][r] - mn);
        rs += p[j][r];
      }
    rs += __shfl_xor(rs, 16);
    rs += __shfl_xor(rs, 32);
    li = li * al + rs;
    // P -> LDS [q][kv], packed b32 writes
#pragma unroll
    for (int j = 0; j < 4; ++j) {
      *(unsigned*)&P_lds[prow + j * 16 + g * 4 + 0] = cvt_pk_bf16(p[j][0], p[j][1]);
      *(unsigned*)&P_lds[prow + j * 16 + g * 4 + 2] = cvt_pk_bf16(p[j][2], p[j][3]);
    }
    // rescale O (alpha is lane-local)
#pragma unroll
    for (int jd = 0; jd < 4; ++jd)
#pragma unroll
      for (int r = 0; r < 4; ++r) o[jd][r] *= al;

    // ---- PV (swapped): o[jd] row=d, col=q ----
    __builtin_amdgcn_s_setprio(1);
#pragma unroll
    for (int ks = 0; ks < 2; ++ks) {
      const bf16x8 ap = *(const bf16x8*)&P_lds[prow + ks * 32 + g * 8];
      bf16x8 bv[4];
#pragma unroll
      for (int jd = 0; jd < 4; ++jd)
        bv[jd] = *(const bf16x8*)&V_lds[cur][(jd * 16 + l15) * 64 +
                                             (((ks * 4 + g) ^ (l15 & 7)) * 8)];
#pragma unroll
      for (int jd = 0; jd < 4; ++jd)
        o[jd] = __builtin_amdgcn_mfma_f32_16x16x32_bf16(bv[jd], ap, o[jd], 0, 0, 0);
    }
    __builtin_amdgcn_s_setprio(0);
  }
#undef STAGE

  // epilogue: lane holds O[d = jd*16+g*4+r][q=l15] -> 8B stores
  const float inv = 1.f / li;
#pragma unroll
  for (int jd = 0; jd < 4; ++jd) {
    uint2 u;
    u.x = cvt_pk_bf16(o[jd][0] * inv, o[jd][1] * inv);
    u.y = cvt_pk_bf16(o[jd][2] * inv, o[jd][3] * inv);
    *(uint2*)&AO[(size_t)(b * SEQ + q) * EDIM + h * HDIM + jd * 16 + g * 4] = u;
  }
}

// ---------------------------------------------------------------------------
// In-place LayerNorm over E=1024, eps=1e-5
// ---------------------------------------------------------------------------
__global__ __launch_bounds__(256) void ln_kernel(float* __restrict__ y,
                                                 const float* __restrict__ gamma,
                                                 const float* __restrict__ beta) {
  const int row = blockIdx.x, tid = threadIdx.x;
  const float4 v = *reinterpret_cast<const float4*>(&y[(size_t)row * EDIM + tid * 4]);
  float s = v.x + v.y + v.z + v.w;
  float s2 = v.x * v.x + v.y * v.y + v.z * v.z + v.w * v.w;
#pragma unroll
  for (int off = 1; off < 64; off <<= 1) {
    s += __shfl_xor(s, off);
    s2 += __shfl_xor(s2, off);
  }
  __shared__ float red[8];
  if ((tid & 63) == 0) {
    red[(tid >> 6) * 2 + 0] = s;
    red[(tid >> 6) * 2 + 1] = s2;
  }
  __syncthreads();
  s = red[0] + red[2] + red[4] + red[6];
  s2 = red[1] + red[3] + red[5] + red[7];
  const float mean = s * (1.f / 1024.f);
  const float var = fmaxf(s2 * (1.f / 1024.f) - mean * mean, 0.f);
  const float rstd = rsqrtf(var + 1e-5f);
  const float4 gm = *reinterpret_cast<const float4*>(&gamma[tid * 4]);
  const float4 be = *reinterpret_cast<const float4*>(&beta[tid * 4]);
  float4 outv;
  outv.x = (v.x - mean) * rstd * gm.x + be.x;
  outv.y = (v.y - mean) * rstd * gm.y + be.y;
  outv.z = (v.z - mean) * rstd * gm.z + be.z;
  outv.w = (v.w - mean) * rstd * gm.w + be.w;
  *reinterpret_cast<float4*>(&y[(size_t)row * EDIM + tid * 4]) = outv;
}

extern "C" void kernel_launch(void* const* d_in, const int* in_sizes, int n_in,
                              void* d_out, int out_size, void* d_ws,
                              size_t ws_size, hipStream_t stream) {
  const float* x = (const float*)d_in[0];
  const float* W_qkv = (const float*)d_in[1];
  const float* b_qkv = (const float*)d_in[2];
  const float* W_proj = (const float*)d_in[3];
  const float* b_proj = (const float*)d_in[4];
  const float* gamma = (const float*)d_in[5];
  const float* beta = (const float*)d_in[6];
  float* out = (float*)d_out;

  uint8_t* p = (uint8_t*)d_ws;
  unsigned short* x_bf = (unsigned short*)p;            p += (size_t)MROWS * EDIM * 2;      // 8 MB
  unsigned short* wqkv_bf = (unsigned short*)p;         p += (size_t)3 * EDIM * EDIM * 2;   // 6 MB
  unsigned short* wproj_bf = (unsigned short*)p;        p += (size_t)EDIM * EDIM * 2;       // 2 MB
  unsigned short* Qb = (unsigned short*)p;              p += (size_t)MROWS * EDIM * 2;      // 8 MB
  unsigned short* Kb = (unsigned short*)p;              p += (size_t)MROWS * EDIM * 2;      // 8 MB
  unsigned short* Vb = (unsigned short*)p;              p += (size_t)MROWS * EDIM * 2;      // 8 MB
  unsigned short* Vtb = (unsigned short*)p;             p += (size_t)MROWS * EDIM * 2;      // 8 MB
  unsigned short* AOb = (unsigned short*)p;             p += (size_t)MROWS * EDIM * 2;      // 8 MB

  // fp32 -> bf16 converts
  cvt_kernel<<<(MROWS * EDIM / 8 + 255) / 256, 256, 0, stream>>>(x, x_bf, MROWS * EDIM);
  cvt_kernel<<<(3 * EDIM * EDIM / 8 + 255) / 256, 256, 0, stream>>>(W_qkv, wqkv_bf, 3 * EDIM * EDIM);
  cvt_kernel<<<(EDIM * EDIM / 8 + 255) / 256, 256, 0, stream>>>(W_proj, wproj_bf, EDIM * EDIM);

  // QKV projection -> Q(*scale)/K/V [B,H,S,D]
  gemm_bf16<0><<<dim3(24, 32), 256, 0, stream>>>(x_bf, wqkv_bf, b_qkv, nullptr,
                                                 Qb, Kb, Vb, nullptr,
                                                 MROWS, 3 * EDIM, EDIM);
  // V -> V^T [B,H,D,S]
  vtrans_kernel<<<dim3(SEQ / 64, BATCH * NHEADS), 256, 0, stream>>>(Vb, Vtb);
  // flash attention -> AO bf16 [B,S,E]
  attn_mfma<<<dim3(SEQ / 128, BATCH * NHEADS), 512, 0, stream>>>(Qb, Kb, Vtb, AOb);
  // out projection + bias + residual -> fp32 y
  gemm_bf16<1><<<dim3(8, 32), 256, 0, stream>>>(AOb, wproj_bf, b_proj, x,
                                                nullptr, nullptr, nullptr, out,
                                                MROWS, EDIM, EDIM);
  // in-place LayerNorm
  ln_kernel<<<MROWS, 256, 0, stream>>>(out, gamma, beta);
}